// Round 6
// baseline (321.050 us; speedup 1.0000x reference)
//
#include <hip/hip_runtime.h>
#include <hip/hip_bf16.h>

// NTM cell on MI355X. B=2048, IN=64, CTRL=512, M=1024, V=64, OUT=64.
// Persistent single kernel (256 blocks x 256 threads, 1 block/CU guaranteed
// co-resident: 52KB LDS, launch_bounds(256,1)), manual device-scope atomic
// grid barriers (counters zeroed by a 16B hipMemsetAsync each launch).
// Phases (R4-proven bodies):
//  P0: fp32->bf16 converts/reorders + split-K read_prev GEMM
//  P1: gates GEMM + fused LSTM -> h
//  P2: heads GEMM (pre_r/pre_w bf16, erase, add, out_h+b_out -> d_out)
//  P3: dual softmax (one row per block-iter) -> rw, rw2, s
//  P4: split-K read_new fused with out-GEMM, atomicAdd into d_out.
// All GEMMs NT bf16 MFMA 16x16x32, BK=128, LDS row stride 136.

typedef unsigned short u16;
typedef __attribute__((ext_vector_type(8))) short bf16x8;
typedef __attribute__((ext_vector_type(4))) float f32x4;

#define MFMA_BF16(a, b, c) __builtin_amdgcn_mfma_f32_16x16x32_bf16((a), (b), (c), 0, 0, 0)
#define LDW 136

__device__ __forceinline__ u16 f2bf(float f) {
    union { float f; unsigned int u; } a; a.f = f;
    return (u16)((a.u + 0x7FFFu + ((a.u >> 16) & 1u)) >> 16);
}

__device__ __forceinline__ void pack_store4(float a0, float a1, float a2, float a3, u16* d) {
    union { __hip_bfloat162 h[2]; uint2 u; } cv;
    cv.h[0] = __float22bfloat162_rn(make_float2(a0, a1));
    cv.h[1] = __float22bfloat162_rn(make_float2(a2, a3));
    *(uint2*)d = cv.u;
}

__device__ __forceinline__ void cvt4(const float* __restrict__ s, u16* __restrict__ d) {
    float4 v = *(const float4*)s;
    pack_store4(v.x, v.y, v.z, v.w, d);
}

__device__ __forceinline__ uint4 cvt8u(const float* __restrict__ s) {
    float4 v0 = *(const float4*)(s);
    float4 v1 = *(const float4*)(s + 4);
    union { __hip_bfloat162 h[4]; uint4 u; } r;
    r.h[0] = __float22bfloat162_rn(make_float2(v0.x, v0.y));
    r.h[1] = __float22bfloat162_rn(make_float2(v0.z, v0.w));
    r.h[2] = __float22bfloat162_rn(make_float2(v1.x, v1.y));
    r.h[3] = __float22bfloat162_rn(make_float2(v1.z, v1.w));
    return r.u;
}

__device__ __forceinline__ uint4 cvt8u_sum4(const float* __restrict__ p, int off) {
    float4 a0 = *(const float4*)(p + off);
    float4 a1 = *(const float4*)(p + 131072 + off);
    float4 a2 = *(const float4*)(p + 262144 + off);
    float4 a3 = *(const float4*)(p + 393216 + off);
    float4 b0 = *(const float4*)(p + off + 4);
    float4 b1 = *(const float4*)(p + 131072 + off + 4);
    float4 b2 = *(const float4*)(p + 262144 + off + 4);
    float4 b3 = *(const float4*)(p + 393216 + off + 4);
    float4 s0{a0.x + a1.x + a2.x + a3.x, a0.y + a1.y + a2.y + a3.y,
              a0.z + a1.z + a2.z + a3.z, a0.w + a1.w + a2.w + a3.w};
    float4 s1{b0.x + b1.x + b2.x + b3.x, b0.y + b1.y + b2.y + b3.y,
              b0.z + b1.z + b2.z + b3.z, b0.w + b1.w + b2.w + b3.w};
    union { __hip_bfloat162 h[4]; uint4 u; } r;
    r.h[0] = __float22bfloat162_rn(make_float2(s0.x, s0.y));
    r.h[1] = __float22bfloat162_rn(make_float2(s0.z, s0.w));
    r.h[2] = __float22bfloat162_rn(make_float2(s1.x, s1.y));
    r.h[3] = __float22bfloat162_rn(make_float2(s1.z, s1.w));
    return r.u;
}

__device__ __forceinline__ float4 bf4_to_f4(uint2 u) {
    union { uint2 u; __hip_bfloat162 h[2]; } c; c.u = u;
    float2 a = __bfloat1622float2(c.h[0]);
    float2 b = __bfloat1622float2(c.h[1]);
    return float4{a.x, a.y, b.x, b.y};
}

__device__ __forceinline__ float sigf(float x) { return 1.f / (1.f + __expf(-x)); }
__device__ __forceinline__ float fast_tanh(float x) { return 1.f - 2.f / (__expf(2.f * x) + 1.f); }

__device__ __forceinline__ float wave_max(float v) {
#pragma unroll
    for (int o = 32; o > 0; o >>= 1) v = fmaxf(v, __shfl_xor(v, o, 64));
    return v;
}
__device__ __forceinline__ float wave_sum(float v) {
#pragma unroll
    for (int o = 32; o > 0; o >>= 1) v += __shfl_xor(v, o, 64);
    return v;
}

// device-scope grid barrier; cnt[phase] zeroed host-side before launch.
__device__ __forceinline__ void gbar(unsigned* cnt, int phase) {
    __syncthreads();
    if (threadIdx.x == 0) {
        __hip_atomic_fetch_add(&cnt[phase], 1u, __ATOMIC_RELEASE, __HIP_MEMORY_SCOPE_AGENT);
        while (__hip_atomic_load(&cnt[phase], __ATOMIC_ACQUIRE, __HIP_MEMORY_SCOPE_AGENT) < 256u)
            __builtin_amdgcn_s_sleep(2);
    }
    __syncthreads();
}

struct KArgs {
    const float *x, *h_prev, *c_prev, *rwp, *memory;
    const float *W_ih, *b_ih, *W_hh, *b_hh;
    const float *W_read, *b_read, *W_write, *b_write;
    const float *W_erase, *b_erase, *W_add, *b_add, *W_out, *b_out;
    float* out;
    u16 *inp_h, *wcat, *Wcat2, *Wo_rn, *memt;
    float* rp;
    u16* hrn;
    u16 *pre_r, *pre_w;
    float *erase, *add;
    u16 *rw_bf, *rw2_bf;
    float* s_buf;
    unsigned* bar;
};

__global__ void __launch_bounds__(256, 1) k_fused(KArgs A)
{
    __shared__ __align__(16) char smem[52224];
    const int tid = threadIdx.x;
    const int w = tid >> 6, lane = tid & 63;
    const int lrow = lane & 15, lq = lane >> 4;
    const int bid = blockIdx.x;

    // ===================== P0: converts + split-K read_prev =====================
    {
        u16* As = (u16*)smem;             // 64 x 136
        u16* Bs = (u16*)(smem + 17408);   // 64 x 136
        for (int vb = bid; vb < 3748; vb += 256) {
            if (vb < 128) {
                const int mb = vb & 31, ks = vb >> 5;
                const int m0 = mb * 64, k0 = ks * 256;
                const int m_loc = tid >> 1, v0 = (tid & 1) * 32;
                f32x4 acc[4] = {};
                for (int kt = 0; kt < 2; ++kt) {
#pragma unroll
                    for (int i = 0; i < 4; ++i) {
                        int idx = i * 256 + tid, r = idx >> 4, c = (idx & 15) * 8;
                        *(uint4*)(&As[r * LDW + c]) = cvt8u(A.rwp + (m0 + r) * 1024 + k0 + kt * 128 + c);
                    }
#pragma unroll
                    for (int j = 0; j < 8; ++j) {
                        float4 q = *(const float4*)(A.memory + (k0 + kt * 128 + m_loc) * 64 + v0 + 4 * j);
                        Bs[(v0 + 4 * j + 0) * LDW + m_loc] = f2bf(q.x);
                        Bs[(v0 + 4 * j + 1) * LDW + m_loc] = f2bf(q.y);
                        Bs[(v0 + 4 * j + 2) * LDW + m_loc] = f2bf(q.z);
                        Bs[(v0 + 4 * j + 3) * LDW + m_loc] = f2bf(q.w);
                    }
                    __syncthreads();
#pragma unroll
                    for (int kk = 0; kk < 128; kk += 32) {
                        bf16x8 a  = *(const bf16x8*)(&As[(16 * w + lrow) * LDW + kk + 8 * lq]);
                        bf16x8 b0 = *(const bf16x8*)(&Bs[(lrow) * LDW + kk + 8 * lq]);
                        bf16x8 b1 = *(const bf16x8*)(&Bs[(16 + lrow) * LDW + kk + 8 * lq]);
                        bf16x8 b2 = *(const bf16x8*)(&Bs[(32 + lrow) * LDW + kk + 8 * lq]);
                        bf16x8 b3 = *(const bf16x8*)(&Bs[(48 + lrow) * LDW + kk + 8 * lq]);
                        acc[0] = MFMA_BF16(a, b0, acc[0]);
                        acc[1] = MFMA_BF16(a, b1, acc[1]);
                        acc[2] = MFMA_BF16(a, b2, acc[2]);
                        acc[3] = MFMA_BF16(a, b3, acc[3]);
                    }
                    __syncthreads();
                }
                float* rps = A.rp + ks * 131072;
#pragma unroll
                for (int nj = 0; nj < 4; ++nj)
#pragma unroll
                    for (int r = 0; r < 4; ++r) {
                        int row = m0 + 16 * w + 4 * lq + r, col = 16 * nj + lrow;
                        rps[row * 64 + col] = acc[nj][r];
                    }
                continue;
            }
            int t = (vb - 128) * 256 + tid;
            if (t < 32768) { int r = t >> 4, c = (t & 15) * 4; cvt4(A.x + r * 64 + c, A.inp_h + r * 576 + c); continue; }
            t -= 32768;
            if (t < 262144) { int r = t >> 7, c = (t & 127) * 4; cvt4(A.h_prev + r * 512 + c, A.inp_h + r * 576 + 64 + c); continue; }
            t -= 262144;
            if (t < 65536) {  // W_ih: gate-interleave rows + col swap (rp|x)
                int r = t >> 5, c = (t & 31) * 4;
                int g = r >> 9, j = r & 511;
                int rn = (j >> 4) * 64 + (g << 4) + (j & 15);
                int cd = (c < 64) ? c + 64 : c - 64;
                cvt4(A.W_ih + r * 128 + c, A.wcat + rn * 640 + cd); continue;
            }
            t -= 65536;
            if (t < 262144) {  // W_hh: gate-interleave rows
                int r = t >> 7, c = (t & 127) * 4;
                int g = r >> 9, j = r & 511;
                int rn = (j >> 4) * 64 + (g << 4) + (j & 15);
                cvt4(A.W_hh + r * 512 + c, A.wcat + rn * 640 + 128 + c); continue;
            }
            t -= 262144;
            if (t < 131072) { cvt4(A.W_read + t * 4, A.Wcat2 + t * 4); continue; }
            t -= 131072;
            if (t < 131072) { cvt4(A.W_write + t * 4, A.Wcat2 + 524288 + t * 4); continue; }
            t -= 131072;
            if (t < 8192) { cvt4(A.W_erase + t * 4, A.Wcat2 + 1048576 + t * 4); continue; }
            t -= 8192;
            if (t < 8192) { cvt4(A.W_add + t * 4, A.Wcat2 + 1081344 + t * 4); continue; }
            t -= 8192;
            if (t < 9216) {  // W_out: h-part -> Wcat2 rows 2176.., rn-part -> Wo_rn
                int r = t / 144, c = (t % 144) * 4;
                if (c < 512) cvt4(A.W_out + r * 576 + c, A.Wcat2 + (2176 + r) * 512 + c);
                else         cvt4(A.W_out + r * 576 + c, A.Wo_rn + r * 64 + (c - 512));
                continue;
            }
            t -= 9216;
            if (t < 16384) {  // memory^T -> memt (64 x 1024)
                int v = t >> 8, m = (t & 255) * 4;
                pack_store4(A.memory[m * 64 + v], A.memory[(m + 1) * 64 + v],
                            A.memory[(m + 2) * 64 + v], A.memory[(m + 3) * 64 + v], A.memt + v * 1024 + m);
            }
        }
    }
    gbar(A.bar, 0);

    // ===================== P1: gates GEMM + fused LSTM =====================
    {
        u16* As = (u16*)smem;             // 128 x 136
        u16* Bs = (u16*)(smem + 34816);   // 64 x 136
        for (int vb = bid; vb < 512; vb += 256) {
            const int m0 = (vb & 15) * 128, bn = vb >> 4;
            const u16* Bbase = A.wcat + bn * 64 * 640;
            f32x4 acc[2][4] = {};
            for (int kt = 0; kt < 5; ++kt) {
#pragma unroll
                for (int i = 0; i < 8; ++i) {
                    int idx = i * 256 + tid, r = idx >> 4, c = (idx & 15) * 8;
                    int ak = kt * 128 + c;
                    uint4 v;
                    if (ak < 64) v = cvt8u_sum4(A.rp, (m0 + r) * 64 + ak);
                    else         v = *(const uint4*)(A.inp_h + (m0 + r) * 576 + (ak - 64));
                    *(uint4*)(&As[r * LDW + c]) = v;
                }
#pragma unroll
                for (int i = 0; i < 4; ++i) {
                    int idx = i * 256 + tid, r = idx >> 4, c = (idx & 15) * 8;
                    *(uint4*)(&Bs[r * LDW + c]) = *(const uint4*)(Bbase + r * 640 + kt * 128 + c);
                }
                __syncthreads();
#pragma unroll
                for (int kk = 0; kk < 128; kk += 32) {
                    bf16x8 a0 = *(const bf16x8*)(&As[(32 * w + lrow) * LDW + kk + 8 * lq]);
                    bf16x8 a1 = *(const bf16x8*)(&As[(32 * w + 16 + lrow) * LDW + kk + 8 * lq]);
                    bf16x8 b0 = *(const bf16x8*)(&Bs[(lrow) * LDW + kk + 8 * lq]);
                    bf16x8 b1 = *(const bf16x8*)(&Bs[(16 + lrow) * LDW + kk + 8 * lq]);
                    bf16x8 b2 = *(const bf16x8*)(&Bs[(32 + lrow) * LDW + kk + 8 * lq]);
                    bf16x8 b3 = *(const bf16x8*)(&Bs[(48 + lrow) * LDW + kk + 8 * lq]);
                    acc[0][0] = MFMA_BF16(a0, b0, acc[0][0]);
                    acc[0][1] = MFMA_BF16(a0, b1, acc[0][1]);
                    acc[0][2] = MFMA_BF16(a0, b2, acc[0][2]);
                    acc[0][3] = MFMA_BF16(a0, b3, acc[0][3]);
                    acc[1][0] = MFMA_BF16(a1, b0, acc[1][0]);
                    acc[1][1] = MFMA_BF16(a1, b1, acc[1][1]);
                    acc[1][2] = MFMA_BF16(a1, b2, acc[1][2]);
                    acc[1][3] = MFMA_BF16(a1, b3, acc[1][3]);
                }
                __syncthreads();
            }
            const int j = bn * 16 + lrow;
            const float bI = A.b_ih[j] + A.b_hh[j];
            const float bF = A.b_ih[512 + j] + A.b_hh[512 + j];
            const float bG = A.b_ih[1024 + j] + A.b_hh[1024 + j];
            const float bO = A.b_ih[1536 + j] + A.b_hh[1536 + j];
#pragma unroll
            for (int mi = 0; mi < 2; ++mi)
#pragma unroll
                for (int r = 0; r < 4; ++r) {
                    int row = m0 + 32 * w + 16 * mi + 4 * lq + r;
                    float ig = sigf(acc[mi][0][r] + bI);
                    float fg = sigf(acc[mi][1][r] + bF);
                    float gg = fast_tanh(acc[mi][2][r] + bG);
                    float og = sigf(acc[mi][3][r] + bO);
                    float c = fg * A.c_prev[row * 512 + j] + ig * gg;
                    A.hrn[row * 512 + j] = f2bf(og * fast_tanh(c));
                }
        }
    }
    gbar(A.bar, 1);

    // ===================== P2: heads GEMM =====================
    {
        u16* As = (u16*)smem;
        u16* Bs = (u16*)(smem + 34816);
        for (int vb = bid; vb < 560; vb += 256) {
            const int m0 = (vb & 15) * 128, bn = vb >> 4;
            const u16* Bbase = A.Wcat2 + bn * 64 * 512;
            f32x4 acc[2][4] = {};
            for (int kt = 0; kt < 4; ++kt) {
#pragma unroll
                for (int i = 0; i < 8; ++i) {
                    int idx = i * 256 + tid, r = idx >> 4, c = (idx & 15) * 8;
                    *(uint4*)(&As[r * LDW + c]) = *(const uint4*)(A.hrn + (m0 + r) * 512 + kt * 128 + c);
                }
#pragma unroll
                for (int i = 0; i < 4; ++i) {
                    int idx = i * 256 + tid, r = idx >> 4, c = (idx & 15) * 8;
                    *(uint4*)(&Bs[r * LDW + c]) = *(const uint4*)(Bbase + r * 512 + kt * 128 + c);
                }
                __syncthreads();
#pragma unroll
                for (int kk = 0; kk < 128; kk += 32) {
                    bf16x8 a0 = *(const bf16x8*)(&As[(32 * w + lrow) * LDW + kk + 8 * lq]);
                    bf16x8 a1 = *(const bf16x8*)(&As[(32 * w + 16 + lrow) * LDW + kk + 8 * lq]);
                    bf16x8 b0 = *(const bf16x8*)(&Bs[(lrow) * LDW + kk + 8 * lq]);
                    bf16x8 b1 = *(const bf16x8*)(&Bs[(16 + lrow) * LDW + kk + 8 * lq]);
                    bf16x8 b2 = *(const bf16x8*)(&Bs[(32 + lrow) * LDW + kk + 8 * lq]);
                    bf16x8 b3 = *(const bf16x8*)(&Bs[(48 + lrow) * LDW + kk + 8 * lq]);
                    acc[0][0] = MFMA_BF16(a0, b0, acc[0][0]);
                    acc[0][1] = MFMA_BF16(a0, b1, acc[0][1]);
                    acc[0][2] = MFMA_BF16(a0, b2, acc[0][2]);
                    acc[0][3] = MFMA_BF16(a0, b3, acc[0][3]);
                    acc[1][0] = MFMA_BF16(a1, b0, acc[1][0]);
                    acc[1][1] = MFMA_BF16(a1, b1, acc[1][1]);
                    acc[1][2] = MFMA_BF16(a1, b2, acc[1][2]);
                    acc[1][3] = MFMA_BF16(a1, b3, acc[1][3]);
                }
                __syncthreads();
            }
#pragma unroll
            for (int mi = 0; mi < 2; ++mi)
#pragma unroll
                for (int nj = 0; nj < 4; ++nj)
#pragma unroll
                    for (int r = 0; r < 4; ++r) {
                        int row = m0 + 32 * w + 16 * mi + 4 * lq + r;
                        int col = bn * 64 + 16 * nj + lrow;
                        float v = acc[mi][nj][r];
                        if (bn < 16)       A.pre_r[row * 1024 + col] = f2bf(v + A.b_read[col]);
                        else if (bn < 32)  A.pre_w[row * 1024 + (col - 1024)] = f2bf(v + A.b_write[col - 1024]);
                        else if (bn == 32) A.erase[row * 64 + (col - 2048)] = sigf(v + A.b_erase[col - 2048]);
                        else if (bn == 33) A.add[row * 64 + (col - 2112)] = fast_tanh(v + A.b_add[col - 2112]);
                        else               A.out[row * 64 + (col - 2176)] = v + A.b_out[col - 2176];
                    }
        }
    }
    gbar(A.bar, 2);

    // ===================== P3: dual softmax (one row per iter) =====================
    {
        float (*red)[4] = (float(*)[4])smem;
        for (int b = bid; b < 2048; b += 256) {
            float4 vr = bf4_to_f4(*(const uint2*)(A.pre_r + b * 1024 + tid * 4));
            float4 vw = bf4_to_f4(*(const uint2*)(A.pre_w + b * 1024 + tid * 4));
            float mr = fmaxf(fmaxf(vr.x, vr.y), fmaxf(vr.z, vr.w));
            float mw = fmaxf(fmaxf(vw.x, vw.y), fmaxf(vw.z, vw.w));
            mr = wave_max(mr); mw = wave_max(mw);
            if (lane == 0) { red[0][w] = mr; red[1][w] = mw; }
            __syncthreads();
            mr = fmaxf(fmaxf(red[0][0], red[0][1]), fmaxf(red[0][2], red[0][3]));
            mw = fmaxf(fmaxf(red[1][0], red[1][1]), fmaxf(red[1][2], red[1][3]));
            float er[4] = {__expf(vr.x - mr), __expf(vr.y - mr), __expf(vr.z - mr), __expf(vr.w - mr)};
            float ew[4] = {__expf(vw.x - mw), __expf(vw.y - mw), __expf(vw.z - mw), __expf(vw.w - mw)};
            float sr = er[0] + er[1] + er[2] + er[3];
            float sw = ew[0] + ew[1] + ew[2] + ew[3];
            sr = wave_sum(sr); sw = wave_sum(sw);
            __syncthreads();
            if (lane == 0) { red[2][w] = sr; red[3][w] = sw; }
            __syncthreads();
            sr = red[2][0] + red[2][1] + red[2][2] + red[2][3];
            sw = red[3][0] + red[3][1] + red[3][2] + red[3][3];
            float isr = 1.f / sr, isw = 1.f / sw, ss = 0.f;
            float a[4], r2[4];
#pragma unroll
            for (int i = 0; i < 4; ++i) {
                a[i] = er[i] * isr;
                r2[i] = a[i] * (ew[i] * isw);
                ss += r2[i];
            }
            pack_store4(a[0], a[1], a[2], a[3], A.rw_bf + b * 1024 + tid * 4);
            pack_store4(r2[0], r2[1], r2[2], r2[3], A.rw2_bf + b * 1024 + tid * 4);
            ss = wave_sum(ss);
            __syncthreads();
            if (lane == 0) red[0][w] = ss;
            __syncthreads();
            if (tid == 0) A.s_buf[b] = red[0][0] + red[0][1] + red[0][2] + red[0][3];
            __syncthreads();
        }
    }
    gbar(A.bar, 3);

    // ===================== P4: split-K read_new + out-GEMM =====================
    {
        u16* As1 = (u16*)smem;            // 32 x 136
        u16* As2 = (u16*)(smem + 8704);   // 32 x 136
        u16* Bs  = (u16*)(smem + 17408);  // 64 x 136
        u16* Ps  = (u16*)(smem + 34816);  // 32 x 72
        const int m0 = (bid & 63) * 32, ks = bid >> 6;
        const int k0 = ks * 256;
        const int mt = w & 1, nb = (w >> 1) * 2;

        f32x4 a1[2] = {}, a2[2] = {};
        for (int kt = 0; kt < 2; ++kt) {
#pragma unroll
            for (int i = 0; i < 2; ++i) {
                int idx = i * 256 + tid, r = idx >> 4, c = (idx & 15) * 8;
                *(uint4*)(&As1[r * LDW + c]) = *(const uint4*)(A.rw_bf + (m0 + r) * 1024 + k0 + kt * 128 + c);
                *(uint4*)(&As2[r * LDW + c]) = *(const uint4*)(A.rw2_bf + (m0 + r) * 1024 + k0 + kt * 128 + c);
            }
#pragma unroll
            for (int i = 0; i < 4; ++i) {
                int idx = i * 256 + tid, r = idx >> 4, c = (idx & 15) * 8;
                *(uint4*)(&Bs[r * LDW + c]) = *(const uint4*)(A.memt + r * 1024 + k0 + kt * 128 + c);
            }
            __syncthreads();
#pragma unroll
            for (int kk = 0; kk < 128; kk += 32) {
                bf16x8 a  = *(const bf16x8*)(&As1[(16 * mt + lrow) * LDW + kk + 8 * lq]);
                bf16x8 c2 = *(const bf16x8*)(&As2[(16 * mt + lrow) * LDW + kk + 8 * lq]);
                bf16x8 b0 = *(const bf16x8*)(&Bs[(16 * nb + lrow) * LDW + kk + 8 * lq]);
                bf16x8 b1 = *(const bf16x8*)(&Bs[(16 * (nb + 1) + lrow) * LDW + kk + 8 * lq]);
                a1[0] = MFMA_BF16(a, b0, a1[0]);
                a1[1] = MFMA_BF16(a, b1, a1[1]);
                a2[0] = MFMA_BF16(c2, b0, a2[0]);
                a2[1] = MFMA_BF16(c2, b1, a2[1]);
            }
            __syncthreads();
        }
#pragma unroll
        for (int i = 0; i < 2; ++i) {
            int idx = i * 256 + tid, r = idx >> 3, c = (idx & 7) * 8;
            *(uint4*)(&Bs[r * LDW + c]) = *(const uint4*)(A.Wo_rn + r * 64 + c);
        }
#pragma unroll
        for (int j = 0; j < 2; ++j)
#pragma unroll
            for (int r = 0; r < 4; ++r) {
                int row_l = 16 * mt + 4 * lq + r, col = 16 * (nb + j) + lrow;
                int row_g = m0 + row_l;
                float p = a1[j][r] - A.erase[row_g * 64 + col] * a2[j][r];
                if (ks == 0) p += A.add[row_g * 64 + col] * A.s_buf[row_g];
                Ps[row_l * 72 + col] = f2bf(p);
            }
        __syncthreads();
        f32x4 o[2] = {};
#pragma unroll
        for (int kk = 0; kk < 64; kk += 32) {
            bf16x8 a  = *(const bf16x8*)(&Ps[(16 * mt + lrow) * 72 + kk + 8 * lq]);
            bf16x8 b0 = *(const bf16x8*)(&Bs[(16 * nb + lrow) * LDW + kk + 8 * lq]);
            bf16x8 b1 = *(const bf16x8*)(&Bs[(16 * (nb + 1) + lrow) * LDW + kk + 8 * lq]);
            o[0] = MFMA_BF16(a, b0, o[0]);
            o[1] = MFMA_BF16(a, b1, o[1]);
        }
#pragma unroll
        for (int j = 0; j < 2; ++j)
#pragma unroll
            for (int r = 0; r < 4; ++r) {
                int row_g = m0 + 16 * mt + 4 * lq + r, col = 16 * (nb + j) + lrow;
                atomicAdd(&A.out[row_g * 64 + col], o[j][r]);
            }
    }
}

extern "C" void kernel_launch(void* const* d_in, const int* in_sizes, int n_in,
                              void* d_out, int out_size, void* d_ws, size_t ws_size,
                              hipStream_t stream)
{
    char* wsp = (char*)d_ws;
    KArgs ka;
    ka.x       = (const float*)d_in[0];
    ka.h_prev  = (const float*)d_in[1];
    ka.c_prev  = (const float*)d_in[2];
    ka.rwp     = (const float*)d_in[3];
    ka.memory  = (const float*)d_in[4];
    ka.W_ih    = (const float*)d_in[5];
    ka.b_ih    = (const float*)d_in[6];
    ka.W_hh    = (const float*)d_in[7];
    ka.b_hh    = (const float*)d_in[8];
    ka.W_read  = (const float*)d_in[9];
    ka.b_read  = (const float*)d_in[10];
    ka.W_write = (const float*)d_in[11];
    ka.b_write = (const float*)d_in[12];
    ka.W_erase = (const float*)d_in[13];
    ka.b_erase = (const float*)d_in[14];
    ka.W_add   = (const float*)d_in[15];
    ka.b_add   = (const float*)d_in[16];
    ka.W_out   = (const float*)d_in[17];
    ka.b_out   = (const float*)d_in[18];
    ka.out     = (float*)d_out;

    ka.inp_h  = (u16*)(wsp + 0);           // 2048x576 bf16 [x | h_prev]
    ka.wcat   = (u16*)(wsp + 2359296);     // 2048x640 bf16 gates weights (reordered)
    ka.memt   = (u16*)(wsp + 4980736);     // 64x1024 bf16 memory^T
    ka.Wcat2  = (u16*)(wsp + 5111808);     // 2240x512 bf16 [Wr;Ww;We;Wa;Wout_h]
    ka.Wo_rn  = (u16*)(wsp + 7405568);     // 64x64 bf16
    ka.rp     = (float*)(wsp + 7413760);   // 4 x 2048x64 fp32 split-K partials
    ka.hrn    = (u16*)(wsp + 9510912);     // 2048x512 bf16 (h)
    ka.pre_r  = (u16*)(wsp + 11608064);    // 2048x1024 bf16
    ka.pre_w  = (u16*)(wsp + 15802368);    // 2048x1024 bf16
    ka.erase  = (float*)(wsp + 19996672);  // 2048x64 fp32
    ka.add    = (float*)(wsp + 20520960);  // 2048x64 fp32
    ka.rw_bf  = (u16*)(wsp + 21045248);    // 2048x1024 bf16
    ka.rw2_bf = (u16*)(wsp + 25239552);    // 2048x1024 bf16
    ka.s_buf  = (float*)(wsp + 29433856);  // 2048 fp32
    ka.bar    = (unsigned*)(wsp + 29442048); // 4 x u32 barrier counters

    hipMemsetAsync(wsp + 29442048, 0, 16, stream);
    k_fused<<<256, 256, 0, stream>>>(ka);
}

// Round 7
// 159.060 us; speedup vs baseline: 2.0184x; 2.0184x over previous
//
#include <hip/hip_runtime.h>
#include <hip/hip_bf16.h>

// NTM cell on MI355X. B=2048, IN=64, CTRL=512, M=1024, V=64, OUT=64.
// 4 dispatches: k_pre (convert + split-K read_prev), k_gates (+fused LSTM),
// k_heads (heads + out_h -> d_out), k_tail (fused dual-softmax + split-K
// read_new + out-GEMM, atomicAdd into d_out).
// All GEMMs NT bf16 MFMA 16x16x32, BK=128, LDS row stride 136.
// NOTE (R6 lesson): persistent single-kernel = 1 block/CU = latency death.
// Oversubscribed multi-dispatch grids win on this chip.

typedef unsigned short u16;
typedef __attribute__((ext_vector_type(8))) short bf16x8;
typedef __attribute__((ext_vector_type(4))) float f32x4;

#define MFMA_BF16(a, b, c) __builtin_amdgcn_mfma_f32_16x16x32_bf16((a), (b), (c), 0, 0, 0)
#define LDW 136

__device__ __forceinline__ u16 f2bf(float f) {
    union { float f; unsigned int u; } a; a.f = f;
    return (u16)((a.u + 0x7FFFu + ((a.u >> 16) & 1u)) >> 16);
}

__device__ __forceinline__ void pack_store4(float a0, float a1, float a2, float a3, u16* d) {
    union { __hip_bfloat162 h[2]; uint2 u; } cv;
    cv.h[0] = __float22bfloat162_rn(make_float2(a0, a1));
    cv.h[1] = __float22bfloat162_rn(make_float2(a2, a3));
    *(uint2*)d = cv.u;
}

__device__ __forceinline__ void cvt4(const float* __restrict__ s, u16* __restrict__ d) {
    float4 v = *(const float4*)s;
    pack_store4(v.x, v.y, v.z, v.w, d);
}

__device__ __forceinline__ uint4 cvt8u(const float* __restrict__ s) {
    float4 v0 = *(const float4*)(s);
    float4 v1 = *(const float4*)(s + 4);
    union { __hip_bfloat162 h[4]; uint4 u; } r;
    r.h[0] = __float22bfloat162_rn(make_float2(v0.x, v0.y));
    r.h[1] = __float22bfloat162_rn(make_float2(v0.z, v0.w));
    r.h[2] = __float22bfloat162_rn(make_float2(v1.x, v1.y));
    r.h[3] = __float22bfloat162_rn(make_float2(v1.z, v1.w));
    return r.u;
}

__device__ __forceinline__ uint4 cvt8u_sum4(const float* __restrict__ p, int off) {
    float4 a0 = *(const float4*)(p + off);
    float4 a1 = *(const float4*)(p + 131072 + off);
    float4 a2 = *(const float4*)(p + 262144 + off);
    float4 a3 = *(const float4*)(p + 393216 + off);
    float4 b0 = *(const float4*)(p + off + 4);
    float4 b1 = *(const float4*)(p + 131072 + off + 4);
    float4 b2 = *(const float4*)(p + 262144 + off + 4);
    float4 b3 = *(const float4*)(p + 393216 + off + 4);
    float4 s0{a0.x + a1.x + a2.x + a3.x, a0.y + a1.y + a2.y + a3.y,
              a0.z + a1.z + a2.z + a3.z, a0.w + a1.w + a2.w + a3.w};
    float4 s1{b0.x + b1.x + b2.x + b3.x, b0.y + b1.y + b2.y + b3.y,
              b0.z + b1.z + b2.z + b3.z, b0.w + b1.w + b2.w + b3.w};
    union { __hip_bfloat162 h[4]; uint4 u; } r;
    r.h[0] = __float22bfloat162_rn(make_float2(s0.x, s0.y));
    r.h[1] = __float22bfloat162_rn(make_float2(s0.z, s0.w));
    r.h[2] = __float22bfloat162_rn(make_float2(s1.x, s1.y));
    r.h[3] = __float22bfloat162_rn(make_float2(s1.z, s1.w));
    return r.u;
}

__device__ __forceinline__ void bfu4_to_f8(uint4 u, float* f) {
    f[0] = __uint_as_float(u.x << 16); f[1] = __uint_as_float(u.x & 0xffff0000u);
    f[2] = __uint_as_float(u.y << 16); f[3] = __uint_as_float(u.y & 0xffff0000u);
    f[4] = __uint_as_float(u.z << 16); f[5] = __uint_as_float(u.z & 0xffff0000u);
    f[6] = __uint_as_float(u.w << 16); f[7] = __uint_as_float(u.w & 0xffff0000u);
}

__device__ __forceinline__ uint4 pack8(const float* v) {
    union { __hip_bfloat162 h[4]; uint4 u; } r;
#pragma unroll
    for (int j = 0; j < 4; ++j) r.h[j] = __float22bfloat162_rn(make_float2(v[2 * j], v[2 * j + 1]));
    return r.u;
}

__device__ __forceinline__ float sigf(float x) { return 1.f / (1.f + __expf(-x)); }
__device__ __forceinline__ float fast_tanh(float x) { return 1.f - 2.f / (__expf(2.f * x) + 1.f); }

// ---------------------------------------------------------------------------
// k_pre: blocks 0..127 = split-K read_prev GEMM (32 m-blocks x 4 K-chunks of
// 256), partials -> rp[ks]. Blocks 128.. = fp32->bf16 convert/reorder jobs.
// ---------------------------------------------------------------------------
__global__ __launch_bounds__(256) void k_pre(
    const float* __restrict__ x, const float* __restrict__ h_prev, const float* __restrict__ rwp,
    const float* __restrict__ memory, const float* __restrict__ W_ih, const float* __restrict__ W_hh,
    const float* __restrict__ W_read, const float* __restrict__ W_write, const float* __restrict__ W_erase,
    const float* __restrict__ W_add, const float* __restrict__ W_out,
    u16* inp_h, u16* wcat, u16* Wcat2, u16* Wo_rn, u16* memt, float* rp)
{
    __shared__ u16 As[64 * LDW];
    __shared__ u16 Bs[64 * LDW];
    const int tid = threadIdx.x;

    if (blockIdx.x < 128) {
        const int mb = blockIdx.x & 31, ks = blockIdx.x >> 5;
        const int w = tid >> 6, lane = tid & 63;
        const int lrow = lane & 15, lq = lane >> 4;
        const int m0 = mb * 64, k0 = ks * 256;
        const int m_loc = tid >> 1, v0 = (tid & 1) * 32;
        f32x4 acc[4] = {};
        for (int kt = 0; kt < 2; ++kt) {
#pragma unroll
            for (int i = 0; i < 4; ++i) {
                int idx = i * 256 + tid, r = idx >> 4, c = (idx & 15) * 8;
                *(uint4*)(&As[r * LDW + c]) = cvt8u(rwp + (m0 + r) * 1024 + k0 + kt * 128 + c);
            }
#pragma unroll
            for (int j = 0; j < 8; ++j) {
                float4 q = *(const float4*)(memory + (k0 + kt * 128 + m_loc) * 64 + v0 + 4 * j);
                Bs[(v0 + 4 * j + 0) * LDW + m_loc] = f2bf(q.x);
                Bs[(v0 + 4 * j + 1) * LDW + m_loc] = f2bf(q.y);
                Bs[(v0 + 4 * j + 2) * LDW + m_loc] = f2bf(q.z);
                Bs[(v0 + 4 * j + 3) * LDW + m_loc] = f2bf(q.w);
            }
            __syncthreads();
#pragma unroll
            for (int kk = 0; kk < 128; kk += 32) {
                bf16x8 a  = *(const bf16x8*)(&As[(16 * w + lrow) * LDW + kk + 8 * lq]);
                bf16x8 b0 = *(const bf16x8*)(&Bs[(lrow) * LDW + kk + 8 * lq]);
                bf16x8 b1 = *(const bf16x8*)(&Bs[(16 + lrow) * LDW + kk + 8 * lq]);
                bf16x8 b2 = *(const bf16x8*)(&Bs[(32 + lrow) * LDW + kk + 8 * lq]);
                bf16x8 b3 = *(const bf16x8*)(&Bs[(48 + lrow) * LDW + kk + 8 * lq]);
                acc[0] = MFMA_BF16(a, b0, acc[0]);
                acc[1] = MFMA_BF16(a, b1, acc[1]);
                acc[2] = MFMA_BF16(a, b2, acc[2]);
                acc[3] = MFMA_BF16(a, b3, acc[3]);
            }
            __syncthreads();
        }
        float* rps = rp + ks * 131072;
#pragma unroll
        for (int nj = 0; nj < 4; ++nj)
#pragma unroll
            for (int r = 0; r < 4; ++r) {
                int row = m0 + 16 * w + 4 * lq + r, col = 16 * nj + lrow;
                rps[row * 64 + col] = acc[nj][r];
            }
        return;
    }

    int t = (blockIdx.x - 128) * 256 + tid;
    if (t < 32768) { int r = t >> 4, c = (t & 15) * 4; cvt4(x + r * 64 + c, inp_h + r * 576 + c); return; }
    t -= 32768;
    if (t < 262144) { int r = t >> 7, c = (t & 127) * 4; cvt4(h_prev + r * 512 + c, inp_h + r * 576 + 64 + c); return; }
    t -= 262144;
    if (t < 65536) {  // W_ih: gate-interleave rows + col swap (rp|x)
        int r = t >> 5, c = (t & 31) * 4;
        int g = r >> 9, j = r & 511;
        int rn = (j >> 4) * 64 + (g << 4) + (j & 15);
        int cd = (c < 64) ? c + 64 : c - 64;
        cvt4(W_ih + r * 128 + c, wcat + rn * 640 + cd); return;
    }
    t -= 65536;
    if (t < 262144) {  // W_hh: gate-interleave rows
        int r = t >> 7, c = (t & 127) * 4;
        int g = r >> 9, j = r & 511;
        int rn = (j >> 4) * 64 + (g << 4) + (j & 15);
        cvt4(W_hh + r * 512 + c, wcat + rn * 640 + 128 + c); return;
    }
    t -= 262144;
    if (t < 131072) { cvt4(W_read + t * 4, Wcat2 + t * 4); return; }
    t -= 131072;
    if (t < 131072) { cvt4(W_write + t * 4, Wcat2 + 524288 + t * 4); return; }
    t -= 131072;
    if (t < 8192) { cvt4(W_erase + t * 4, Wcat2 + 1048576 + t * 4); return; }
    t -= 8192;
    if (t < 8192) { cvt4(W_add + t * 4, Wcat2 + 1081344 + t * 4); return; }
    t -= 8192;
    if (t < 9216) {  // W_out: h-part -> Wcat2 rows 2176.., rn-part -> Wo_rn
        int r = t / 144, c = (t % 144) * 4;
        if (c < 512) cvt4(W_out + r * 576 + c, Wcat2 + (2176 + r) * 512 + c);
        else         cvt4(W_out + r * 576 + c, Wo_rn + r * 64 + (c - 512));
        return;
    }
    t -= 9216;
    if (t < 16384) {  // memory^T -> memt (64 x 1024)
        int v = t >> 8, m = (t & 255) * 4;
        pack_store4(memory[m * 64 + v], memory[(m + 1) * 64 + v],
                    memory[(m + 2) * 64 + v], memory[(m + 3) * 64 + v], memt + v * 1024 + m);
    }
}

// ---------------------------------------------------------------------------
// gates GEMM + fused LSTM. A-K layout: [read_prev(64, sum of 4 fp32 partials)
// | x(64) | h_prev(512)]. wcat rows pre-reordered: block col = gate*16+(j&15).
// ---------------------------------------------------------------------------
__global__ __launch_bounds__(256) void k_gates(const u16* __restrict__ inp_h, const float* __restrict__ rp,
                                               const u16* __restrict__ wcat,
                                               const float* __restrict__ b_ih, const float* __restrict__ b_hh,
                                               const float* __restrict__ c_prev, u16* __restrict__ hrn)
{
    __shared__ u16 As[128 * LDW];
    __shared__ u16 Bs[64 * LDW];
    const int tid = threadIdx.x, w = tid >> 6, lane = tid & 63;
    const int lrow = lane & 15, lq = lane >> 4;
    const int m0 = blockIdx.x * 128, bn = blockIdx.y;
    const u16* Bbase = wcat + bn * 64 * 640;
    f32x4 acc[2][4] = {};
    for (int kt = 0; kt < 5; ++kt) {
#pragma unroll
        for (int i = 0; i < 8; ++i) {
            int idx = i * 256 + tid, r = idx >> 4, c = (idx & 15) * 8;
            int ak = kt * 128 + c;
            uint4 v;
            if (ak < 64) v = cvt8u_sum4(rp, (m0 + r) * 64 + ak);
            else         v = *(const uint4*)(inp_h + (m0 + r) * 576 + (ak - 64));
            *(uint4*)(&As[r * LDW + c]) = v;
        }
#pragma unroll
        for (int i = 0; i < 4; ++i) {
            int idx = i * 256 + tid, r = idx >> 4, c = (idx & 15) * 8;
            *(uint4*)(&Bs[r * LDW + c]) = *(const uint4*)(Bbase + r * 640 + kt * 128 + c);
        }
        __syncthreads();
#pragma unroll
        for (int kk = 0; kk < 128; kk += 32) {
            bf16x8 a0 = *(const bf16x8*)(&As[(32 * w + lrow) * LDW + kk + 8 * lq]);
            bf16x8 a1 = *(const bf16x8*)(&As[(32 * w + 16 + lrow) * LDW + kk + 8 * lq]);
            bf16x8 b0 = *(const bf16x8*)(&Bs[(lrow) * LDW + kk + 8 * lq]);
            bf16x8 b1 = *(const bf16x8*)(&Bs[(16 + lrow) * LDW + kk + 8 * lq]);
            bf16x8 b2 = *(const bf16x8*)(&Bs[(32 + lrow) * LDW + kk + 8 * lq]);
            bf16x8 b3 = *(const bf16x8*)(&Bs[(48 + lrow) * LDW + kk + 8 * lq]);
            acc[0][0] = MFMA_BF16(a0, b0, acc[0][0]);
            acc[0][1] = MFMA_BF16(a0, b1, acc[0][1]);
            acc[0][2] = MFMA_BF16(a0, b2, acc[0][2]);
            acc[0][3] = MFMA_BF16(a0, b3, acc[0][3]);
            acc[1][0] = MFMA_BF16(a1, b0, acc[1][0]);
            acc[1][1] = MFMA_BF16(a1, b1, acc[1][1]);
            acc[1][2] = MFMA_BF16(a1, b2, acc[1][2]);
            acc[1][3] = MFMA_BF16(a1, b3, acc[1][3]);
        }
        __syncthreads();
    }
    const int j = bn * 16 + lrow;
    const float bI = b_ih[j] + b_hh[j];
    const float bF = b_ih[512 + j] + b_hh[512 + j];
    const float bG = b_ih[1024 + j] + b_hh[1024 + j];
    const float bO = b_ih[1536 + j] + b_hh[1536 + j];
#pragma unroll
    for (int mi = 0; mi < 2; ++mi)
#pragma unroll
        for (int r = 0; r < 4; ++r) {
            int row = m0 + 32 * w + 16 * mi + 4 * lq + r;
            float ig = sigf(acc[mi][0][r] + bI);
            float fg = sigf(acc[mi][1][r] + bF);
            float gg = fast_tanh(acc[mi][2][r] + bG);
            float og = sigf(acc[mi][3][r] + bO);
            float c = fg * c_prev[row * 512 + j] + ig * gg;
            hrn[row * 512 + j] = f2bf(og * fast_tanh(c));
        }
}

// ---------------------------------------------------------------------------
// heads: [pre_read | pre_write | erase | add | out_h] = h @ Wcat2^T + biases.
// grid (16, 35). pre_r/pre_w stored bf16. bn==34 writes out_h directly to out.
// ---------------------------------------------------------------------------
__global__ __launch_bounds__(256) void k_heads(const u16* __restrict__ hrn, const u16* __restrict__ Wcat2,
                                               const float* __restrict__ b_read, const float* __restrict__ b_write,
                                               const float* __restrict__ b_erase, const float* __restrict__ b_add,
                                               const float* __restrict__ b_out,
                                               u16* __restrict__ pre_r, u16* __restrict__ pre_w,
                                               float* __restrict__ erase, float* __restrict__ add,
                                               float* __restrict__ out)
{
    __shared__ u16 As[128 * LDW];
    __shared__ u16 Bs[64 * LDW];
    const int tid = threadIdx.x, w = tid >> 6, lane = tid & 63;
    const int lrow = lane & 15, lq = lane >> 4;
    const int m0 = blockIdx.x * 128, bn = blockIdx.y;
    const u16* Bbase = Wcat2 + bn * 64 * 512;
    f32x4 acc[2][4] = {};
    for (int kt = 0; kt < 4; ++kt) {
#pragma unroll
        for (int i = 0; i < 8; ++i) {
            int idx = i * 256 + tid, r = idx >> 4, c = (idx & 15) * 8;
            *(uint4*)(&As[r * LDW + c]) = *(const uint4*)(hrn + (m0 + r) * 512 + kt * 128 + c);
        }
#pragma unroll
        for (int i = 0; i < 4; ++i) {
            int idx = i * 256 + tid, r = idx >> 4, c = (idx & 15) * 8;
            *(uint4*)(&Bs[r * LDW + c]) = *(const uint4*)(Bbase + r * 512 + kt * 128 + c);
        }
        __syncthreads();
#pragma unroll
        for (int kk = 0; kk < 128; kk += 32) {
            bf16x8 a0 = *(const bf16x8*)(&As[(32 * w + lrow) * LDW + kk + 8 * lq]);
            bf16x8 a1 = *(const bf16x8*)(&As[(32 * w + 16 + lrow) * LDW + kk + 8 * lq]);
            bf16x8 b0 = *(const bf16x8*)(&Bs[(lrow) * LDW + kk + 8 * lq]);
            bf16x8 b1 = *(const bf16x8*)(&Bs[(16 + lrow) * LDW + kk + 8 * lq]);
            bf16x8 b2 = *(const bf16x8*)(&Bs[(32 + lrow) * LDW + kk + 8 * lq]);
            bf16x8 b3 = *(const bf16x8*)(&Bs[(48 + lrow) * LDW + kk + 8 * lq]);
            acc[0][0] = MFMA_BF16(a0, b0, acc[0][0]);
            acc[0][1] = MFMA_BF16(a0, b1, acc[0][1]);
            acc[0][2] = MFMA_BF16(a0, b2, acc[0][2]);
            acc[0][3] = MFMA_BF16(a0, b3, acc[0][3]);
            acc[1][0] = MFMA_BF16(a1, b0, acc[1][0]);
            acc[1][1] = MFMA_BF16(a1, b1, acc[1][1]);
            acc[1][2] = MFMA_BF16(a1, b2, acc[1][2]);
            acc[1][3] = MFMA_BF16(a1, b3, acc[1][3]);
        }
        __syncthreads();
    }
#pragma unroll
    for (int mi = 0; mi < 2; ++mi)
#pragma unroll
        for (int nj = 0; nj < 4; ++nj)
#pragma unroll
            for (int r = 0; r < 4; ++r) {
                int row = m0 + 32 * w + 16 * mi + 4 * lq + r;
                int col = bn * 64 + 16 * nj + lrow;
                float v = acc[mi][nj][r];
                if (bn < 16)       pre_r[row * 1024 + col] = f2bf(v + b_read[col]);
                else if (bn < 32)  pre_w[row * 1024 + (col - 1024)] = f2bf(v + b_write[col - 1024]);
                else if (bn == 32) erase[row * 64 + (col - 2048)] = sigf(v + b_erase[col - 2048]);
                else if (bn == 33) add[row * 64 + (col - 2112)] = fast_tanh(v + b_add[col - 2112]);
                else               out[row * 64 + (col - 2176)] = v + b_out[col - 2176];
            }
}

// ---------------------------------------------------------------------------
// k_tail: 256 blocks = 128 m-blocks (16 rows) x 2 K-halves.
// Per block: dual softmax for its 16 rows (full M=1024, redundant across the
// 2 K-halves) -> rw/rw2 for this half into LDS; read_new GEMM (K=512);
// partial rn through Wo_rn^T; atomicAdd into out (seeded with out_h + b_out).
// ---------------------------------------------------------------------------
#define SLDW 520   // 512 + 8 pad (keeps 16B alignment per row)

__global__ __launch_bounds__(256) void k_tail(const u16* __restrict__ pre_r, const u16* __restrict__ pre_w,
                                              const u16* __restrict__ memt, const u16* __restrict__ Wo_rn,
                                              const float* __restrict__ erase, const float* __restrict__ add,
                                              float* __restrict__ out)
{
    __shared__ u16 rwS[16 * SLDW];
    __shared__ u16 rw2S[16 * SLDW];
    __shared__ u16 BsP[64 * LDW];
    __shared__ u16 Ps[16 * 72];
    __shared__ float s_sh[16];
    const int tid = threadIdx.x, w = tid >> 6, lane = tid & 63;
    const int lrow = lane & 15, lq = lane >> 4;
    const int mb = blockIdx.x >> 1, kh = blockIdx.x & 1;
    const int m0 = mb * 16, k0 = kh * 512;

    // --- dual softmax: row = tid>>4 (16 rows), 16 threads/row, 64 cols each ---
    {
        const int row = tid >> 4, c16 = tid & 15;
        const int row_g = m0 + row;
        const u16* prp = pre_r + row_g * 1024;
        const u16* pwp = pre_w + row_g * 1024;
        float vr[64], vw[64];
#pragma unroll
        for (int q = 0; q < 8; ++q) {
            bfu4_to_f8(*(const uint4*)(prp + q * 128 + c16 * 8), vr + 8 * q);
            bfu4_to_f8(*(const uint4*)(pwp + q * 128 + c16 * 8), vw + 8 * q);
        }
        float mr = vr[0], mw = vw[0];
#pragma unroll
        for (int i = 1; i < 64; ++i) { mr = fmaxf(mr, vr[i]); mw = fmaxf(mw, vw[i]); }
#pragma unroll
        for (int o = 1; o < 16; o <<= 1) {
            mr = fmaxf(mr, __shfl_xor(mr, o, 64));
            mw = fmaxf(mw, __shfl_xor(mw, o, 64));
        }
        float sr = 0.f, sw = 0.f;
#pragma unroll
        for (int i = 0; i < 64; ++i) {
            vr[i] = __expf(vr[i] - mr); sr += vr[i];
            vw[i] = __expf(vw[i] - mw); sw += vw[i];
        }
#pragma unroll
        for (int o = 1; o < 16; o <<= 1) {
            sr += __shfl_xor(sr, o, 64);
            sw += __shfl_xor(sw, o, 64);
        }
        const float isr = 1.f / sr, isw = 1.f / sw;
        float ss = 0.f;
#pragma unroll
        for (int q = 0; q < 8; ++q) {
            float a8[8], r8[8];
#pragma unroll
            for (int i = 0; i < 8; ++i) {
                float a = vr[8 * q + i] * isr;
                float r2 = a * (vw[8 * q + i] * isw);
                a8[i] = a; r8[i] = r2;
                ss += r2;
            }
            if ((q >> 2) == kh) {   // this half's cols -> LDS
                int cb = (q - 4 * kh) * 128 + c16 * 8;
                *(uint4*)(&rwS[row * SLDW + cb])  = pack8(a8);
                *(uint4*)(&rw2S[row * SLDW + cb]) = pack8(r8);
            }
        }
#pragma unroll
        for (int o = 1; o < 16; o <<= 1) ss += __shfl_xor(ss, o, 64);
        if (c16 == 0) s_sh[row] = ss;
    }
    __syncthreads();

    // --- read_new GEMM: 16 rows x 64 cols, K=512 (this half) ---
    f32x4 acc1 = {}, acc2 = {};
    for (int kt = 0; kt < 4; ++kt) {
#pragma unroll
        for (int i = 0; i < 4; ++i) {
            int idx = i * 256 + tid, r = idx >> 4, c = (idx & 15) * 8;
            *(uint4*)(&BsP[r * LDW + c]) = *(const uint4*)(memt + r * 1024 + k0 + kt * 128 + c);
        }
        __syncthreads();
#pragma unroll
        for (int kk = 0; kk < 128; kk += 32) {
            bf16x8 a1 = *(const bf16x8*)(&rwS[lrow * SLDW + kt * 128 + kk + 8 * lq]);
            bf16x8 a2 = *(const bf16x8*)(&rw2S[lrow * SLDW + kt * 128 + kk + 8 * lq]);
            bf16x8 b  = *(const bf16x8*)(&BsP[(16 * w + lrow) * LDW + kk + 8 * lq]);
            acc1 = MFMA_BF16(a1, b, acc1);
            acc2 = MFMA_BF16(a2, b, acc2);
        }
        __syncthreads();
    }

    // --- epilogue -> Ps (bf16); stage Wo_rn into BsP concurrently ---
#pragma unroll
    for (int r = 0; r < 4; ++r) {
        int row_l = 4 * lq + r, col = 16 * w + lrow;
        int row_g = m0 + row_l;
        float p = acc1[r] - erase[row_g * 64 + col] * acc2[r];
        if (kh == 0) p += add[row_g * 64 + col] * s_sh[row_l];
        Ps[row_l * 72 + col] = f2bf(p);
    }
#pragma unroll
    for (int i = 0; i < 2; ++i) {
        int idx = i * 256 + tid, r = idx >> 3, c = (idx & 7) * 8;
        *(uint4*)(&BsP[r * LDW + c]) = *(const uint4*)(Wo_rn + r * 64 + c);
    }
    __syncthreads();

    // --- out-GEMM: (16 x 64) @ Wo_rn^T, K=64; atomicAdd into seeded out ---
    f32x4 acc3 = {};
#pragma unroll
    for (int kk = 0; kk < 64; kk += 32) {
        bf16x8 a = *(const bf16x8*)(&Ps[lrow * 72 + kk + 8 * lq]);
        bf16x8 b = *(const bf16x8*)(&BsP[(16 * w + lrow) * LDW + kk + 8 * lq]);
        acc3 = MFMA_BF16(a, b, acc3);
    }
#pragma unroll
    for (int r = 0; r < 4; ++r) {
        int row_g = m0 + 4 * lq + r, col = 16 * w + lrow;
        atomicAdd(&out[row_g * 64 + col], acc3[r]);
    }
}

extern "C" void kernel_launch(void* const* d_in, const int* in_sizes, int n_in,
                              void* d_out, int out_size, void* d_ws, size_t ws_size,
                              hipStream_t stream)
{
    const float* x        = (const float*)d_in[0];
    const float* h_prev   = (const float*)d_in[1];
    const float* c_prev   = (const float*)d_in[2];
    const float* rwp      = (const float*)d_in[3];
    const float* memory   = (const float*)d_in[4];
    const float* W_ih     = (const float*)d_in[5];
    const float* b_ih     = (const float*)d_in[6];
    const float* W_hh     = (const float*)d_in[7];
    const float* b_hh     = (const float*)d_in[8];
    const float* W_read   = (const float*)d_in[9];
    const float* b_read   = (const float*)d_in[10];
    const float* W_write  = (const float*)d_in[11];
    const float* b_write  = (const float*)d_in[12];
    const float* W_erase  = (const float*)d_in[13];
    const float* b_erase  = (const float*)d_in[14];
    const float* W_add    = (const float*)d_in[15];
    const float* b_add    = (const float*)d_in[16];
    const float* W_out    = (const float*)d_in[17];
    const float* b_out    = (const float*)d_in[18];
    float* out = (float*)d_out;

    char* wsp = (char*)d_ws;
    u16*   inp_h  = (u16*)(wsp + 0);           // 2048x576 bf16 [x | h_prev]
    u16*   wcat   = (u16*)(wsp + 2359296);     // 2048x640 bf16 gates weights (reordered)
    u16*   memt   = (u16*)(wsp + 4980736);     // 64x1024 bf16 memory^T
    u16*   Wcat2  = (u16*)(wsp + 5111808);     // 2240x512 bf16 [Wr;Ww;We;Wa;Wout_h]
    u16*   Wo_rn  = (u16*)(wsp + 7405568);     // 64x64 bf16
    float* rp     = (float*)(wsp + 7413760);   // 4 x 2048x64 fp32 split-K partials
    u16*   hrn    = (u16*)(wsp + 9510912);     // 2048x512 bf16 (h)
    u16*   pre_r  = (u16*)(wsp + 11608064);    // 2048x1024 bf16
    u16*   pre_w  = (u16*)(wsp + 15802368);    // 2048x1024 bf16
    float* erase  = (float*)(wsp + 19996672);  // 2048x64 fp32
    float* add    = (float*)(wsp + 20520960);  // 2048x64 fp32

    k_pre<<<3748, 256, 0, stream>>>(x, h_prev, rwp, memory, W_ih, W_hh, W_read, W_write,
                                    W_erase, W_add, W_out,
                                    inp_h, wcat, Wcat2, Wo_rn, memt, rp);
    k_gates<<<dim3(16, 32), 256, 0, stream>>>(inp_h, rp, wcat, b_ih, b_hh, c_prev, hrn);
    k_heads<<<dim3(16, 35), 256, 0, stream>>>(hrn, Wcat2, b_read, b_write, b_erase, b_add, b_out,
                                              pre_r, pre_w, erase, add, out);
    k_tail<<<256, 256, 0, stream>>>(pre_r, pre_w, memt, Wo_rn, erase, add, out);
}

// Round 8
// 158.130 us; speedup vs baseline: 2.0303x; 1.0059x over previous
//
#include <hip/hip_runtime.h>
#include <hip/hip_bf16.h>

// NTM cell on MI355X. B=2048, IN=64, CTRL=512, M=1024, V=64, OUT=64.
// 4 dispatches: k_pre (convert->tile-major + split-K read_prev), k_gates
// (+fused LSTM), k_heads, k_tail (softmax + read_new + out-GEMM).
// k_gates/k_heads stage A/B via __builtin_amdgcn_global_load_lds width=16
// from fragment-ordered tile-major buffers: chunk layout [oct][row], 16B
// chunk = one lane's bf16x8 MFMA fragment. DMA is a linear copy; frag reads
// hit banks at row*4 mod 32 -> uniform 2-way aliasing (free per m136).

typedef unsigned short u16;
typedef __attribute__((ext_vector_type(8))) short bf16x8;
typedef __attribute__((ext_vector_type(4))) float f32x4;

#define MFMA_BF16(a, b, c) __builtin_amdgcn_mfma_f32_16x16x32_bf16((a), (b), (c), 0, 0, 0)
#define LDW 136

__device__ __forceinline__ void dma16(const void* g, void* l) {
    __builtin_amdgcn_global_load_lds(
        (const __attribute__((address_space(1))) unsigned int*)g,
        (__attribute__((address_space(3))) unsigned int*)l, 16, 0, 0);
}

__device__ __forceinline__ u16 f2bf(float f) {
    union { float f; unsigned int u; } a; a.f = f;
    return (u16)((a.u + 0x7FFFu + ((a.u >> 16) & 1u)) >> 16);
}

__device__ __forceinline__ void pack_store4(float a0, float a1, float a2, float a3, u16* d) {
    union { __hip_bfloat162 h[2]; uint2 u; } cv;
    cv.h[0] = __float22bfloat162_rn(make_float2(a0, a1));
    cv.h[1] = __float22bfloat162_rn(make_float2(a2, a3));
    *(uint2*)d = cv.u;
}

__device__ __forceinline__ void cvt4(const float* __restrict__ s, u16* __restrict__ d) {
    float4 v = *(const float4*)s;
    pack_store4(v.x, v.y, v.z, v.w, d);
}

__device__ __forceinline__ uint4 cvt8u(const float* __restrict__ s) {
    float4 v0 = *(const float4*)(s);
    float4 v1 = *(const float4*)(s + 4);
    union { __hip_bfloat162 h[4]; uint4 u; } r;
    r.h[0] = __float22bfloat162_rn(make_float2(v0.x, v0.y));
    r.h[1] = __float22bfloat162_rn(make_float2(v0.z, v0.w));
    r.h[2] = __float22bfloat162_rn(make_float2(v1.x, v1.y));
    r.h[3] = __float22bfloat162_rn(make_float2(v1.z, v1.w));
    return r.u;
}

__device__ __forceinline__ uint4 cvt8u_sum4(const float* __restrict__ p, int off) {
    float4 a0 = *(const float4*)(p + off);
    float4 a1 = *(const float4*)(p + 131072 + off);
    float4 a2 = *(const float4*)(p + 262144 + off);
    float4 a3 = *(const float4*)(p + 393216 + off);
    float4 b0 = *(const float4*)(p + off + 4);
    float4 b1 = *(const float4*)(p + 131072 + off + 4);
    float4 b2 = *(const float4*)(p + 262144 + off + 4);
    float4 b3 = *(const float4*)(p + 393216 + off + 4);
    float4 s0{a0.x + a1.x + a2.x + a3.x, a0.y + a1.y + a2.y + a3.y,
              a0.z + a1.z + a2.z + a3.z, a0.w + a1.w + a2.w + a3.w};
    float4 s1{b0.x + b1.x + b2.x + b3.x, b0.y + b1.y + b2.y + b3.y,
              b0.z + b1.z + b2.z + b3.z, b0.w + b1.w + b2.w + b3.w};
    union { __hip_bfloat162 h[4]; uint4 u; } r;
    r.h[0] = __float22bfloat162_rn(make_float2(s0.x, s0.y));
    r.h[1] = __float22bfloat162_rn(make_float2(s0.z, s0.w));
    r.h[2] = __float22bfloat162_rn(make_float2(s1.x, s1.y));
    r.h[3] = __float22bfloat162_rn(make_float2(s1.z, s1.w));
    return r.u;
}

__device__ __forceinline__ void bfu4_to_f8(uint4 u, float* f) {
    f[0] = __uint_as_float(u.x << 16); f[1] = __uint_as_float(u.x & 0xffff0000u);
    f[2] = __uint_as_float(u.y << 16); f[3] = __uint_as_float(u.y & 0xffff0000u);
    f[4] = __uint_as_float(u.z << 16); f[5] = __uint_as_float(u.z & 0xffff0000u);
    f[6] = __uint_as_float(u.w << 16); f[7] = __uint_as_float(u.w & 0xffff0000u);
}

__device__ __forceinline__ uint4 pack8(const float* v) {
    union { __hip_bfloat162 h[4]; uint4 u; } r;
#pragma unroll
    for (int j = 0; j < 4; ++j) r.h[j] = __float22bfloat162_rn(make_float2(v[2 * j], v[2 * j + 1]));
    return r.u;
}

__device__ __forceinline__ float sigf(float x) { return 1.f / (1.f + __expf(-x)); }
__device__ __forceinline__ float fast_tanh(float x) { return 1.f - 2.f / (__expf(2.f * x) + 1.f); }

// ---------------------------------------------------------------------------
// k_pre: blocks 0..127 = split-K read_prev GEMM. Blocks 128.. = fp32->bf16
// converts writing TILE-MAJOR layouts (chunk [oct][row], 8 bf16 per chunk).
// ---------------------------------------------------------------------------
__global__ __launch_bounds__(256) void k_pre(
    const float* __restrict__ x, const float* __restrict__ h_prev, const float* __restrict__ rwp,
    const float* __restrict__ memory, const float* __restrict__ W_ih, const float* __restrict__ W_hh,
    const float* __restrict__ W_read, const float* __restrict__ W_write, const float* __restrict__ W_erase,
    const float* __restrict__ W_add, const float* __restrict__ W_out,
    u16* x_t, u16* ht_t, u16* wcat_t, u16* Wcat2_t, u16* Wo_rn, u16* memt, float* rp)
{
    __shared__ u16 As[64 * LDW];
    __shared__ u16 Bs[64 * LDW];
    const int tid = threadIdx.x;

    if (blockIdx.x < 128) {
        const int mb = blockIdx.x & 31, ks = blockIdx.x >> 5;
        const int w = tid >> 6, lane = tid & 63;
        const int lrow = lane & 15, lq = lane >> 4;
        const int m0 = mb * 64, k0 = ks * 256;
        const int m_loc = tid >> 1, v0 = (tid & 1) * 32;
        f32x4 acc[4] = {};
        for (int kt = 0; kt < 2; ++kt) {
#pragma unroll
            for (int i = 0; i < 4; ++i) {
                int idx = i * 256 + tid, r = idx >> 4, c = (idx & 15) * 8;
                *(uint4*)(&As[r * LDW + c]) = cvt8u(rwp + (m0 + r) * 1024 + k0 + kt * 128 + c);
            }
#pragma unroll
            for (int j = 0; j < 8; ++j) {
                float4 q = *(const float4*)(memory + (k0 + kt * 128 + m_loc) * 64 + v0 + 4 * j);
                Bs[(v0 + 4 * j + 0) * LDW + m_loc] = f2bf(q.x);
                Bs[(v0 + 4 * j + 1) * LDW + m_loc] = f2bf(q.y);
                Bs[(v0 + 4 * j + 2) * LDW + m_loc] = f2bf(q.z);
                Bs[(v0 + 4 * j + 3) * LDW + m_loc] = f2bf(q.w);
            }
            __syncthreads();
#pragma unroll
            for (int kk = 0; kk < 128; kk += 32) {
                bf16x8 a  = *(const bf16x8*)(&As[(16 * w + lrow) * LDW + kk + 8 * lq]);
                bf16x8 b0 = *(const bf16x8*)(&Bs[(lrow) * LDW + kk + 8 * lq]);
                bf16x8 b1 = *(const bf16x8*)(&Bs[(16 + lrow) * LDW + kk + 8 * lq]);
                bf16x8 b2 = *(const bf16x8*)(&Bs[(32 + lrow) * LDW + kk + 8 * lq]);
                bf16x8 b3 = *(const bf16x8*)(&Bs[(48 + lrow) * LDW + kk + 8 * lq]);
                acc[0] = MFMA_BF16(a, b0, acc[0]);
                acc[1] = MFMA_BF16(a, b1, acc[1]);
                acc[2] = MFMA_BF16(a, b2, acc[2]);
                acc[3] = MFMA_BF16(a, b3, acc[3]);
            }
            __syncthreads();
        }
        float* rps = rp + ks * 131072;
#pragma unroll
        for (int nj = 0; nj < 4; ++nj)
#pragma unroll
            for (int r = 0; r < 4; ++r) {
                int row = m0 + 16 * w + 4 * lq + r, col = 16 * nj + lrow;
                rps[row * 64 + col] = acc[nj][r];
            }
        return;
    }

    int t = (blockIdx.x - 128) * 256 + tid;
    if (t < 32768) {  // x -> x_t[mt][oct8][row128]
        int r = t >> 4, c = (t & 15) * 4;
        cvt4(x + r * 64 + c, x_t + ((r >> 7) * 8 + (c >> 3)) * 1024 + (r & 127) * 8 + (c & 7));
        return;
    }
    t -= 32768;
    if (t < 262144) {  // h_prev -> ht_t[mt][oct64][row128]
        int r = t >> 7, c = (t & 127) * 4;
        cvt4(h_prev + r * 512 + c, ht_t + ((r >> 7) * 64 + (c >> 3)) * 1024 + (r & 127) * 8 + (c & 7));
        return;
    }
    t -= 262144;
    if (t < 65536) {  // W_ih (gate-interleave rows, col swap rp|x) -> wcat_t[bn][kt0][oct][row64]
        int r = t >> 5, c = (t & 31) * 4;
        int g = r >> 9, j = r & 511;
        int bn = j >> 4, row64 = (g << 4) + (j & 15);
        int cd = (c < 64) ? c + 64 : c - 64;
        cvt4(W_ih + r * 128 + c, wcat_t + (bn * 5) * 8192 + (cd >> 3) * 512 + row64 * 8 + (cd & 7));
        return;
    }
    t -= 65536;
    if (t < 262144) {  // W_hh -> wcat_t[bn][kt1..4][oct][row64]
        int r = t >> 7, c = (t & 127) * 4;
        int g = r >> 9, j = r & 511;
        int bn = j >> 4, row64 = (g << 4) + (j & 15);
        int cd = 128 + c;
        cvt4(W_hh + r * 512 + c, wcat_t + (bn * 5 + (cd >> 7)) * 8192 + ((cd >> 3) & 15) * 512 + row64 * 8 + (cd & 7));
        return;
    }
    t -= 262144;
    if (t < 131072) {  // W_read -> Wcat2_t bn 0..15
        int r = t >> 7, c = (t & 127) * 4;
        cvt4(W_read + t * 4, Wcat2_t + ((r >> 6) * 4 + (c >> 7)) * 8192 + ((c >> 3) & 15) * 512 + (r & 63) * 8 + (c & 7));
        return;
    }
    t -= 131072;
    if (t < 131072) {  // W_write -> bn 16..31
        int r = t >> 7, c = (t & 127) * 4;
        cvt4(W_write + t * 4, Wcat2_t + ((16 + (r >> 6)) * 4 + (c >> 7)) * 8192 + ((c >> 3) & 15) * 512 + (r & 63) * 8 + (c & 7));
        return;
    }
    t -= 131072;
    if (t < 8192) {  // W_erase -> bn 32
        int r = t >> 7, c = (t & 127) * 4;
        cvt4(W_erase + t * 4, Wcat2_t + (32 * 4 + (c >> 7)) * 8192 + ((c >> 3) & 15) * 512 + r * 8 + (c & 7));
        return;
    }
    t -= 8192;
    if (t < 8192) {  // W_add -> bn 33
        int r = t >> 7, c = (t & 127) * 4;
        cvt4(W_add + t * 4, Wcat2_t + (33 * 4 + (c >> 7)) * 8192 + ((c >> 3) & 15) * 512 + r * 8 + (c & 7));
        return;
    }
    t -= 8192;
    if (t < 9216) {  // W_out: h-part -> bn 34; rn-part -> Wo_rn
        int r = t / 144, c = (t % 144) * 4;
        if (c < 512)
            cvt4(W_out + r * 576 + c, Wcat2_t + (34 * 4 + (c >> 7)) * 8192 + ((c >> 3) & 15) * 512 + r * 8 + (c & 7));
        else
            cvt4(W_out + r * 576 + c, Wo_rn + r * 64 + (c - 512));
        return;
    }
    t -= 9216;
    if (t < 16384) {  // memory^T -> memt (64 x 1024)
        int v = t >> 8, m = (t & 255) * 4;
        pack_store4(memory[m * 64 + v], memory[(m + 1) * 64 + v],
                    memory[(m + 2) * 64 + v], memory[(m + 3) * 64 + v], memt + v * 1024 + m);
    }
}

// ---------------------------------------------------------------------------
// gates GEMM + fused LSTM. A-K = [rp(64) | x(64) | h(512)]. LDS tiles are
// fragment-chunk-ordered [oct16][rows]; A/B staged by global_load_lds except
// the rp strip (kt0, octs 0..7) which goes via VGPR sum4-convert.
// ---------------------------------------------------------------------------
__global__ __launch_bounds__(256) void k_gates(const u16* __restrict__ x_t, const u16* __restrict__ ht_t,
                                               const float* __restrict__ rp, const u16* __restrict__ wcat_t,
                                               const float* __restrict__ b_ih, const float* __restrict__ b_hh,
                                               const float* __restrict__ c_prev, u16* __restrict__ hrn_t)
{
    __shared__ u16 As[16384];   // 16 oct x 128 row x 8
    __shared__ u16 Bs[8192];    // 16 oct x 64 row x 8
    const int tid = threadIdx.x, w = tid >> 6, lane = tid & 63;
    const int lrow = lane & 15, lq = lane >> 4;
    const int mt = blockIdx.x, bn = blockIdx.y;
    const int m0 = mt * 128;
    f32x4 acc[2][4] = {};
    for (int kt = 0; kt < 5; ++kt) {
        if (kt == 0) {
            // octs 0..7 = rp (VGPR sum4-cvt), octs 8..15 = x (DMA)
#pragma unroll
            for (int i = 0; i < 4; ++i) {
                int cp = i * 256 + tid;             // chunk = oct*128 + row
                int oct = cp >> 7, row = cp & 127;
                *(uint4*)(&As[cp * 8]) = cvt8u_sum4(rp, (m0 + row) * 64 + oct * 8);
            }
#pragma unroll
            for (int i = 0; i < 4; ++i) {
                int cp = i * 256 + tid;
                dma16(x_t + mt * 8192 + cp * 8, &As[(1024 + (i * 256 + w * 64)) * 8]);
            }
        } else {
#pragma unroll
            for (int i = 0; i < 8; ++i) {
                int cp = i * 256 + tid;
                dma16(ht_t + mt * 65536 + (kt - 1) * 16384 + cp * 8, &As[(i * 256 + w * 64) * 8]);
            }
        }
#pragma unroll
        for (int i = 0; i < 4; ++i) {
            int cp = i * 256 + tid;
            dma16(wcat_t + (bn * 5 + kt) * 8192 + cp * 8, &Bs[(i * 256 + w * 64) * 8]);
        }
        __syncthreads();
#pragma unroll
        for (int kk = 0; kk < 128; kk += 32) {
            const int ob = (kk >> 3) + lq;
            bf16x8 a0 = *(const bf16x8*)(&As[ob * 1024 + (32 * w + lrow) * 8]);
            bf16x8 a1 = *(const bf16x8*)(&As[ob * 1024 + (32 * w + 16 + lrow) * 8]);
            bf16x8 b0 = *(const bf16x8*)(&Bs[ob * 512 + (lrow) * 8]);
            bf16x8 b1 = *(const bf16x8*)(&Bs[ob * 512 + (16 + lrow) * 8]);
            bf16x8 b2 = *(const bf16x8*)(&Bs[ob * 512 + (32 + lrow) * 8]);
            bf16x8 b3 = *(const bf16x8*)(&Bs[ob * 512 + (48 + lrow) * 8]);
            acc[0][0] = MFMA_BF16(a0, b0, acc[0][0]);
            acc[0][1] = MFMA_BF16(a0, b1, acc[0][1]);
            acc[0][2] = MFMA_BF16(a0, b2, acc[0][2]);
            acc[0][3] = MFMA_BF16(a0, b3, acc[0][3]);
            acc[1][0] = MFMA_BF16(a1, b0, acc[1][0]);
            acc[1][1] = MFMA_BF16(a1, b1, acc[1][1]);
            acc[1][2] = MFMA_BF16(a1, b2, acc[1][2]);
            acc[1][3] = MFMA_BF16(a1, b3, acc[1][3]);
        }
        __syncthreads();
    }
    const int j = bn * 16 + lrow;
    const float bI = b_ih[j] + b_hh[j];
    const float bF = b_ih[512 + j] + b_hh[512 + j];
    const float bG = b_ih[1024 + j] + b_hh[1024 + j];
    const float bO = b_ih[1536 + j] + b_hh[1536 + j];
#pragma unroll
    for (int mi = 0; mi < 2; ++mi)
#pragma unroll
        for (int r = 0; r < 4; ++r) {
            int row = m0 + 32 * w + 16 * mi + 4 * lq + r;
            float ig = sigf(acc[mi][0][r] + bI);
            float fg = sigf(acc[mi][1][r] + bF);
            float gg = fast_tanh(acc[mi][2][r] + bG);
            float og = sigf(acc[mi][3][r] + bO);
            float c = fg * c_prev[row * 512 + j] + ig * gg;
            // h -> tile-major hrn_t[mt][oct][row]
            hrn_t[(row >> 7) * 65536 + (j >> 3) * 1024 + (row & 127) * 8 + (j & 7)] =
                f2bf(og * fast_tanh(c));
        }
}

// ---------------------------------------------------------------------------
// heads: [pre_read | pre_write | erase | add | out_h] = h @ Wcat2^T + biases.
// grid (16, 35). A (hrn_t) and B (Wcat2_t) both staged via global_load_lds.
// ---------------------------------------------------------------------------
__global__ __launch_bounds__(256) void k_heads(const u16* __restrict__ hrn_t, const u16* __restrict__ Wcat2_t,
                                               const float* __restrict__ b_read, const float* __restrict__ b_write,
                                               const float* __restrict__ b_erase, const float* __restrict__ b_add,
                                               const float* __restrict__ b_out,
                                               u16* __restrict__ pre_r, u16* __restrict__ pre_w,
                                               float* __restrict__ erase, float* __restrict__ add,
                                               float* __restrict__ out)
{
    __shared__ u16 As[16384];
    __shared__ u16 Bs[8192];
    const int tid = threadIdx.x, w = tid >> 6, lane = tid & 63;
    const int lrow = lane & 15, lq = lane >> 4;
    const int mt = blockIdx.x, bn = blockIdx.y;
    const int m0 = mt * 128;
    f32x4 acc[2][4] = {};
    for (int kt = 0; kt < 4; ++kt) {
#pragma unroll
        for (int i = 0; i < 8; ++i) {
            int cp = i * 256 + tid;
            dma16(hrn_t + mt * 65536 + kt * 16384 + cp * 8, &As[(i * 256 + w * 64) * 8]);
        }
#pragma unroll
        for (int i = 0; i < 4; ++i) {
            int cp = i * 256 + tid;
            dma16(Wcat2_t + (bn * 4 + kt) * 8192 + cp * 8, &Bs[(i * 256 + w * 64) * 8]);
        }
        __syncthreads();
#pragma unroll
        for (int kk = 0; kk < 128; kk += 32) {
            const int ob = (kk >> 3) + lq;
            bf16x8 a0 = *(const bf16x8*)(&As[ob * 1024 + (32 * w + lrow) * 8]);
            bf16x8 a1 = *(const bf16x8*)(&As[ob * 1024 + (32 * w + 16 + lrow) * 8]);
            bf16x8 b0 = *(const bf16x8*)(&Bs[ob * 512 + (lrow) * 8]);
            bf16x8 b1 = *(const bf16x8*)(&Bs[ob * 512 + (16 + lrow) * 8]);
            bf16x8 b2 = *(const bf16x8*)(&Bs[ob * 512 + (32 + lrow) * 8]);
            bf16x8 b3 = *(const bf16x8*)(&Bs[ob * 512 + (48 + lrow) * 8]);
            acc[0][0] = MFMA_BF16(a0, b0, acc[0][0]);
            acc[0][1] = MFMA_BF16(a0, b1, acc[0][1]);
            acc[0][2] = MFMA_BF16(a0, b2, acc[0][2]);
            acc[0][3] = MFMA_BF16(a0, b3, acc[0][3]);
            acc[1][0] = MFMA_BF16(a1, b0, acc[1][0]);
            acc[1][1] = MFMA_BF16(a1, b1, acc[1][1]);
            acc[1][2] = MFMA_BF16(a1, b2, acc[1][2]);
            acc[1][3] = MFMA_BF16(a1, b3, acc[1][3]);
        }
        __syncthreads();
    }
#pragma unroll
    for (int mi = 0; mi < 2; ++mi)
#pragma unroll
        for (int nj = 0; nj < 4; ++nj)
#pragma unroll
            for (int r = 0; r < 4; ++r) {
                int row = m0 + 32 * w + 16 * mi + 4 * lq + r;
                int col = bn * 64 + 16 * nj + lrow;
                float v = acc[mi][nj][r];
                if (bn < 16)       pre_r[row * 1024 + col] = f2bf(v + b_read[col]);
                else if (bn < 32)  pre_w[row * 1024 + (col - 1024)] = f2bf(v + b_write[col - 1024]);
                else if (bn == 32) erase[row * 64 + (col - 2048)] = sigf(v + b_erase[col - 2048]);
                else if (bn == 33) add[row * 64 + (col - 2112)] = fast_tanh(v + b_add[col - 2112]);
                else               out[row * 64 + (col - 2176)] = v + b_out[col - 2176];
            }
}

// ---------------------------------------------------------------------------
// k_tail: 256 blocks = 128 m-blocks (16 rows) x 2 K-halves.
// dual softmax (redundant across halves) -> LDS; read_new GEMM (K=512);
// partial rn through Wo_rn^T; atomicAdd into out (seeded with out_h + b_out).
// ---------------------------------------------------------------------------
#define SLDW 520

__global__ __launch_bounds__(256) void k_tail(const u16* __restrict__ pre_r, const u16* __restrict__ pre_w,
                                              const u16* __restrict__ memt, const u16* __restrict__ Wo_rn,
                                              const float* __restrict__ erase, const float* __restrict__ add,
                                              float* __restrict__ out)
{
    __shared__ u16 rwS[16 * SLDW];
    __shared__ u16 rw2S[16 * SLDW];
    __shared__ u16 BsP[64 * LDW];
    __shared__ u16 Ps[16 * 72];
    __shared__ float s_sh[16];
    const int tid = threadIdx.x, w = tid >> 6, lane = tid & 63;
    const int lrow = lane & 15, lq = lane >> 4;
    const int mb = blockIdx.x >> 1, kh = blockIdx.x & 1;
    const int m0 = mb * 16, k0 = kh * 512;

    {
        const int row = tid >> 4, c16 = tid & 15;
        const int row_g = m0 + row;
        const u16* prp = pre_r + row_g * 1024;
        const u16* pwp = pre_w + row_g * 1024;
        float vr[64], vw[64];
#pragma unroll
        for (int q = 0; q < 8; ++q) {
            bfu4_to_f8(*(const uint4*)(prp + q * 128 + c16 * 8), vr + 8 * q);
            bfu4_to_f8(*(const uint4*)(pwp + q * 128 + c16 * 8), vw + 8 * q);
        }
        float mr = vr[0], mw = vw[0];
#pragma unroll
        for (int i = 1; i < 64; ++i) { mr = fmaxf(mr, vr[i]); mw = fmaxf(mw, vw[i]); }
#pragma unroll
        for (int o = 1; o < 16; o <<= 1) {
            mr = fmaxf(mr, __shfl_xor(mr, o, 64));
            mw = fmaxf(mw, __shfl_xor(mw, o, 64));
        }
        float sr = 0.f, sw = 0.f;
#pragma unroll
        for (int i = 0; i < 64; ++i) {
            vr[i] = __expf(vr[i] - mr); sr += vr[i];
            vw[i] = __expf(vw[i] - mw); sw += vw[i];
        }
#pragma unroll
        for (int o = 1; o < 16; o <<= 1) {
            sr += __shfl_xor(sr, o, 64);
            sw += __shfl_xor(sw, o, 64);
        }
        const float isr = 1.f / sr, isw = 1.f / sw;
        float ss = 0.f;
#pragma unroll
        for (int q = 0; q < 8; ++q) {
            float a8[8], r8[8];
#pragma unroll
            for (int i = 0; i < 8; ++i) {
                float a = vr[8 * q + i] * isr;
                float r2 = a * (vw[8 * q + i] * isw);
                a8[i] = a; r8[i] = r2;
                ss += r2;
            }
            if ((q >> 2) == kh) {
                int cb = (q - 4 * kh) * 128 + c16 * 8;
                *(uint4*)(&rwS[row * SLDW + cb])  = pack8(a8);
                *(uint4*)(&rw2S[row * SLDW + cb]) = pack8(r8);
            }
        }
#pragma unroll
        for (int o = 1; o < 16; o <<= 1) ss += __shfl_xor(ss, o, 64);
        if (c16 == 0) s_sh[row] = ss;
    }
    __syncthreads();

    f32x4 acc1 = {}, acc2 = {};
    for (int kt = 0; kt < 4; ++kt) {
#pragma unroll
        for (int i = 0; i < 4; ++i) {
            int idx = i * 256 + tid, r = idx >> 4, c = (idx & 15) * 8;
            *(uint4*)(&BsP[r * LDW + c]) = *(const uint4*)(memt + r * 1024 + k0 + kt * 128 + c);
        }
        __syncthreads();
#pragma unroll
        for (int kk = 0; kk < 128; kk += 32) {
            bf16x8 a1 = *(const bf16x8*)(&rwS[lrow * SLDW + kt * 128 + kk + 8 * lq]);
            bf16x8 a2 = *(const bf16x8*)(&rw2S[lrow * SLDW + kt * 128 + kk + 8 * lq]);
            bf16x8 b  = *(const bf16x8*)(&BsP[(16 * w + lrow) * LDW + kk + 8 * lq]);
            acc1 = MFMA_BF16(a1, b, acc1);
            acc2 = MFMA_BF16(a2, b, acc2);
        }
        __syncthreads();
    }

#pragma unroll
    for (int r = 0; r < 4; ++r) {
        int row_l = 4 * lq + r, col = 16 * w + lrow;
        int row_g = m0 + row_l;
        float p = acc1[r] - erase[row_g * 64 + col] * acc2[r];
        if (kh == 0) p += add[row_g * 64 + col] * s_sh[row_l];
        Ps[row_l * 72 + col] = f2bf(p);
    }
#pragma unroll
    for (int i = 0; i < 2; ++i) {
        int idx = i * 256 + tid, r = idx >> 3, c = (idx & 7) * 8;
        *(uint4*)(&BsP[r * LDW + c]) = *(const uint4*)(Wo_rn + r * 64 + c);
    }
    __syncthreads();

    f32x4 acc3 = {};
#pragma unroll
    for (int kk = 0; kk < 64; kk += 32) {
        bf16x8 a = *(const bf16x8*)(&Ps[lrow * 72 + kk + 8 * lq]);
        bf16x8 b = *(const bf16x8*)(&BsP[(16 * w + lrow) * LDW + kk + 8 * lq]);
        acc3 = MFMA_BF16(a, b, acc3);
    }
#pragma unroll
    for (int r = 0; r < 4; ++r) {
        int row_g = m0 + 4 * lq + r, col = 16 * w + lrow;
        atomicAdd(&out[row_g * 64 + col], acc3[r]);
    }
}

extern "C" void kernel_launch(void* const* d_in, const int* in_sizes, int n_in,
                              void* d_out, int out_size, void* d_ws, size_t ws_size,
                              hipStream_t stream)
{
    const float* x        = (const float*)d_in[0];
    const float* h_prev   = (const float*)d_in[1];
    const float* c_prev   = (const float*)d_in[2];
    const float* rwp      = (const float*)d_in[3];
    const float* memory   = (const float*)d_in[4];
    const float* W_ih     = (const float*)d_in[5];
    const float* b_ih     = (const float*)d_in[6];
    const float* W_hh     = (const float*)d_in[7];
    const float* b_hh     = (const float*)d_in[8];
    const float* W_read   = (const float*)d_in[9];
    const float* b_read   = (const float*)d_in[10];
    const float* W_write  = (const float*)d_in[11];
    const float* b_write  = (const float*)d_in[12];
    const float* W_erase  = (const float*)d_in[13];
    const float* b_erase  = (const float*)d_in[14];
    const float* W_add    = (const float*)d_in[15];
    const float* b_add    = (const float*)d_in[16];
    const float* W_out    = (const float*)d_in[17];
    const float* b_out    = (const float*)d_in[18];
    float* out = (float*)d_out;

    char* wsp = (char*)d_ws;
    u16*   x_t     = (u16*)(wsp + 0);           // 16 x 8oct x 128row x 8  (256 KB)
    u16*   ht_t    = (u16*)(wsp + 262144);      // 16 x 64oct x 128row x 8 (2 MB)
    u16*   wcat_t  = (u16*)(wsp + 2359296);     // 32bn x 5kt x 16oct x 64row x 8
    u16*   memt    = (u16*)(wsp + 4980736);     // 64 x 1024 bf16 memory^T
    u16*   Wcat2_t = (u16*)(wsp + 5111808);     // 35bn x 4kt x 16oct x 64row x 8
    u16*   Wo_rn   = (u16*)(wsp + 7405568);     // 64x64 bf16
    float* rp      = (float*)(wsp + 7413760);   // 4 x 2048x64 fp32 split-K partials
    u16*   hrn_t   = (u16*)(wsp + 9510912);     // 16 x 64oct x 128row x 8 (2 MB)
    u16*   pre_r   = (u16*)(wsp + 11608064);    // 2048x1024 bf16
    u16*   pre_w   = (u16*)(wsp + 15802368);    // 2048x1024 bf16
    float* erase   = (float*)(wsp + 19996672);  // 2048x64 fp32
    float* add     = (float*)(wsp + 20520960);  // 2048x64 fp32

    k_pre<<<3748, 256, 0, stream>>>(x, h_prev, rwp, memory, W_ih, W_hh, W_read, W_write,
                                    W_erase, W_add, W_out,
                                    x_t, ht_t, wcat_t, Wcat2_t, Wo_rn, memt, rp);
    k_gates<<<dim3(16, 32), 256, 0, stream>>>(x_t, ht_t, rp, wcat_t, b_ih, b_hh, c_prev, hrn_t);
    k_heads<<<dim3(16, 35), 256, 0, stream>>>(hrn_t, Wcat2_t, b_read, b_write, b_erase, b_add, b_out,
                                              pre_r, pre_w, erase, add, out);
    k_tail<<<256, 256, 0, stream>>>(pre_r, pre_w, memt, Wo_rn, erase, add, out);
}